// Round 4
// baseline (686.506 us; speedup 1.0000x reference)
//
#include <hip/hip_runtime.h>
#include <math.h>

// PQC simulator: 16 qubits, 4 layers, batch 256.
// Storage index = FINAL logical index (CNOT-chain perms deferred & pre-composed):
//   storage[s] init = in[s ^ (s>>4)]
//   gate (t,q): pairs {s, s^m'}, m' = prefixXOR^(4-t)(e_q); role(s)=parity(w'&s)
// 5 passes, dim-14 LDS tiles (128KB), 512 threads. Each pass = 2-3 register
// clusters of <=5 gates; cluster 1 fuses the global load, the last cluster
// fuses the global store. LDS uses a GF(2)-linear XOR swizzle folded into
// compile-time combo tables.

#define NT 512

constexpr unsigned mprime(int t, int q) {
    int u = 4 - t, b = 15 - q;
    unsigned m = 0;
    for (int s = 0; s <= b; ++s) {
        int n = u - 1 + s;
        if ((n & s) == s) m |= 1u << (b - s);   // Lucas: C(n,s) odd iff (n&s)==s
    }
    return m;
}
constexpr unsigned wprime(int t, int q) {
    int u = 4 - t, b = 15 - q;
    unsigned w = 0;
    for (int i = 0; b + i <= 15; ++i)
        if ((u & i) == i) w |= 1u << (b + i);
    return w;
}
constexpr int parity16(unsigned x) { int p = 0; for (int j = 0; j < 16; ++j) p ^= (int)((x >> j) & 1u); return p; }
constexpr int hibit(unsigned x) { int b = 0; for (int j = 0; j < 16; ++j) if ((x >> j) & 1u) b = j; return b; }
constexpr unsigned SWZc(unsigned l) { return l ^ ((l >> 4) & 0xFu) ^ ((l >> 8) & 0xFu) ^ ((l >> 12) & 0x3u); }

struct Cluster {
    int c;
    int gi[5];
    unsigned wglob[5], rho[5], lam[5];
    unsigned gcombo[32], pcombo[32];
    int np[14];
};
struct PassDef {
    int nclust;
    unsigned basis[14];
    int fb0, fb1;
    Cluster cl[3];
};

constexpr PassDef make_pass(int P) {
    PassDef pd{};
    int tq[14][2] = {}; int ng = 0;
    if (P == 0) { for (int q = 2; q <= 15; ++q) { tq[ng][0] = 0; tq[ng][1] = q; ++ng; } }
    if (P == 1) { tq[ng][0] = 0; tq[ng][1] = 0; ++ng; tq[ng][0] = 0; tq[ng][1] = 1; ++ng;
                  for (int q = 4; q <= 15; ++q) { tq[ng][0] = 1; tq[ng][1] = q; ++ng; } }
    if (P == 2) { for (int q = 0; q <= 3; ++q) { tq[ng][0] = 1; tq[ng][1] = q; ++ng; }
                  for (int q = 6; q <= 15; ++q) { tq[ng][0] = 2; tq[ng][1] = q; ++ng; } }
    if (P == 3) { for (int q = 0; q <= 5; ++q) { tq[ng][0] = 2; tq[ng][1] = q; ++ng; }
                  for (int q = 10; q <= 15; ++q) { tq[ng][0] = 3; tq[ng][1] = q; ++ng; } }
    if (P == 4) { for (int q = 0; q <= 9; ++q) { tq[ng][0] = 3; tq[ng][1] = q; ++ng; } }

    // basis (systematic: dense low bits + cleared-low residues with high pivots)
    if (P == 0) { for (int j = 0; j < 14; ++j) pd.basis[j] = 1u << j; pd.fb0 = 14; pd.fb1 = 15; }
    if (P == 1) { for (int j = 0; j < 12; ++j) pd.basis[j] = 1u << j;
                  pd.basis[12] = 1u << 14; pd.basis[13] = 1u << 15; pd.fb0 = 12; pd.fb1 = 13; }
    if (P == 2) { for (int j = 0; j < 10; ++j) pd.basis[j] = 1u << j;
                  pd.basis[10] = 0x1800u; pd.basis[11] = 0x3000u; pd.basis[12] = 0x6400u; pd.basis[13] = 0xCC00u;
                  pd.fb0 = 10; pd.fb1 = 11; }
    if (P == 3) { for (int j = 0; j < 8; ++j) pd.basis[j] = 1u << j;
                  pd.basis[8] = 0x0500u; pd.basis[9] = 0x0A00u; pd.basis[10] = 0x1500u;
                  pd.basis[11] = 0x2A00u; pd.basis[12] = 0x5500u; pd.basis[13] = 0xAA00u;
                  pd.fb0 = 8; pd.fb1 = 9; }
    if (P == 4) { for (int j = 0; j < 4; ++j) pd.basis[j] = 1u << j; pd.basis[4] = 0x70u;
                  for (int j = 5; j < 14; ++j) pd.basis[j] = 1u << (j + 2);
                  pd.fb0 = 4; pd.fb1 = 5; }

    // coverage check: basis pivots + free bits must tile all 16 positions
    {
        unsigned cov = (1u << pd.fb0) | (1u << pd.fb1);
        for (int j = 0; j < 14; ++j) cov |= 1u << hibit(pd.basis[j]);
        int chk = 1 / (cov == 0xFFFFu ? 1 : 0); (void)chk;
    }

    int csz[3] = {0, 0, 0}; int ncl = 3;
    if (P == 0 || P == 1 || P == 2) { csz[0] = 5; csz[1] = 5; csz[2] = 4; ncl = 3; }
    if (P == 3) { csz[0] = 5; csz[1] = 5; csz[2] = 2; ncl = 3; }
    if (P == 4) { csz[0] = 5; csz[1] = 5; ncl = 2; }
    pd.nclust = ncl;

    int bpiv[14] = {};
    for (int j = 0; j < 14; ++j) bpiv[j] = hibit(pd.basis[j]);

    int gpos = 0;
    for (int ci = 0; ci < ncl; ++ci) {
        Cluster& C = pd.cl[ci];
        C.c = csz[ci];
        unsigned mus[5] = {}, ms[5] = {};
        for (int g = 0; g < C.c; ++g) {
            int t = tq[gpos][0], q = tq[gpos][1]; ++gpos;
            C.gi[g] = t * 16 + q;
            unsigned m = mprime(t, q), w = wprime(t, q);
            ms[g] = m; C.wglob[g] = w;
            unsigned r = m, mu = 0;
            for (int pv = 15; pv >= 0; --pv) {
                if (!((r >> pv) & 1u)) continue;
                for (int j = 0; j < 14; ++j)
                    if (bpiv[j] == pv) { mu |= 1u << j; r ^= pd.basis[j]; break; }
            }
            mu = mu / (r == 0 ? 1u : 0u);           // trap: mask not in span
            unsigned rec = 0;
            for (int j = 0; j < 14; ++j) if ((mu >> j) & 1u) rec ^= pd.basis[j];
            int ver = 1 / (rec == m ? 1 : 0); (void)ver;  // trap: bad reduction
            mus[g] = mu;
            unsigned rho = 0;
            for (int j = 0; j < 14; ++j) rho |= (unsigned)parity16(w & pd.basis[j]) << j;
            C.rho[g] = rho;
        }
        for (int g = 0; g < C.c; ++g) {
            unsigned l = 0;
            for (int k = 0; k < C.c; ++k) l |= (unsigned)parity16(C.wglob[g] & ms[k]) << k;
            C.lam[g] = l;
        }
        unsigned pmask = 0;
        for (int g = 0; g < C.c; ++g) {
            int pv = hibit(mus[g]);
            int chk = 1 / (((pmask >> pv) & 1u) ? 0 : 1); (void)chk;  // trap: dup pivot
            pmask |= 1u << pv;
        }
        int nn = 0;
        for (int b = 0; b < 14; ++b) if (!((pmask >> b) & 1u)) C.np[nn++] = b;
        for (int v = 0; v < (1 << C.c); ++v) {
            unsigned wc = 0, gc = 0;
            for (int g = 0; g < C.c; ++g) if ((v >> g) & 1) { wc ^= mus[g]; gc ^= ms[g]; }
            C.gcombo[v] = gc; C.pcombo[v] = SWZc(wc);
        }
    }
    return pd;
}

// ---- prep: fuse RZ*RY*RX per (layer,qubit) into 8 floats in d_ws ----
__global__ void prep_gates(const float* __restrict__ params, float* __restrict__ utab) {
    int i = threadIdx.x;
    if (i >= 64) return;
    int t = i >> 4, q = i & 15;
    float ax = params[(t * 16 + q) * 3 + 0];
    float ay = params[(t * 16 + q) * 3 + 1];
    float az = params[(t * 16 + q) * 3 + 2];
    float cx = cosf(0.5f * ax), sx = sinf(0.5f * ax);
    float cy = cosf(0.5f * ay), sy = sinf(0.5f * ay);
    float cz = cosf(0.5f * az), sz = sinf(0.5f * az);
    float A = cy * cx, B = sy * sx, C = sy * cx, D = cy * sx;
    float* o = utab + i * 8;
    o[0] = cz * A + sz * B;  o[1] = cz * B - sz * A;
    o[2] = -cz * C - sz * D; o[3] = sz * C - cz * D;
    o[4] = cz * C + sz * D;  o[5] = sz * C - cz * D;
    o[6] = cz * A + sz * B;  o[7] = sz * A - cz * B;
}

__device__ __forceinline__ unsigned swz(unsigned l) {
    return l ^ ((l >> 4) & 0xFu) ^ ((l >> 8) & 0xFu) ^ ((l >> 12) & 0x3u);
}

template <int P, int CI>
__device__ __forceinline__ void do_cluster(float2* __restrict__ tile,
        unsigned base, size_t boff, float2* __restrict__ st,
        const float* __restrict__ utab,
        const float* __restrict__ in_re, const float* __restrict__ in_im) {
    constexpr PassDef pd = make_pass(P);
    constexpr int CC = pd.cl[CI].c;
    constexpr int EL = 1 << CC;
    constexpr int NC = (1 << (14 - CC)) / NT;
    constexpr bool FIRST = (CI == 0);
    constexpr bool LAST = (CI + 1 == pd.nclust);

    #pragma unroll
    for (int cc = 0; cc < NC; ++cc) {
        unsigned idx = (unsigned)threadIdx.x + (unsigned)(cc * NT);
        unsigned tb = 0;
        #pragma unroll
        for (int i = 0; i < 14 - CC; ++i) tb |= ((idx >> i) & 1u) << pd.cl[CI].np[i];
        unsigned gtb = base;
        #pragma unroll
        for (int j = 0; j < 14; ++j) if ((tb >> j) & 1u) gtb ^= pd.basis[j];
        unsigned ptb = swz(tb);

        float xr[EL], xi[EL];
        #pragma unroll
        for (int v = 0; v < EL; ++v) {
            if constexpr (FIRST) {
                unsigned ga = gtb ^ pd.cl[CI].gcombo[v];
                if constexpr (P == 0) {
                    unsigned g4 = ga ^ (ga >> 4);      // gather absorbs final perm
                    xr[v] = in_re[boff + g4]; xi[v] = in_im[boff + g4];
                } else {
                    float2 f = st[boff + ga]; xr[v] = f.x; xi[v] = f.y;
                }
            } else {
                float2 f = tile[ptb ^ pd.cl[CI].pcombo[v]]; xr[v] = f.x; xi[v] = f.y;
            }
        }

        #pragma unroll
        for (int g = 0; g < CC; ++g) {
            const float* u = utab + pd.cl[CI].gi[g] * 8;
            int r0 = (__popc(pd.cl[CI].rho[g] & tb) + __popc(pd.cl[CI].wglob[g] & base)) & 1;
            float u0r = u[0], u0i = u[1], u1r = u[2], u1i = u[3];
            float u2r = u[4], u2i = u[5], u3r = u[6], u3i = u[7];
            float Ar = r0 ? u3r : u0r, Ai = r0 ? u3i : u0i;
            float Br = r0 ? u2r : u1r, Bi = r0 ? u2i : u1i;
            float Cr = r0 ? u1r : u2r, Ci_ = r0 ? u1i : u2i;
            float Dr = r0 ? u0r : u3r, Di = r0 ? u0i : u3i;
            #pragma unroll
            for (int v = 0; v < EL; ++v) {
                if (v & (1 << g)) continue;
                int cpar = __popc(pd.cl[CI].lam[g] & (unsigned)v) & 1;   // folds
                int y = v | (1 << g);
                float axr = xr[v], axi = xi[v], ayr = xr[y], ayi = xi[y];
                if (cpar == 0) {
                    xr[v] = Ar * axr - Ai * axi + Br * ayr - Bi * ayi;
                    xi[v] = Ar * axi + Ai * axr + Br * ayi + Bi * ayr;
                    xr[y] = Cr * axr - Ci_ * axi + Dr * ayr - Di * ayi;
                    xi[y] = Cr * axi + Ci_ * axr + Dr * ayi + Di * ayr;
                } else {
                    xr[v] = Dr * axr - Di * axi + Cr * ayr - Ci_ * ayi;
                    xi[v] = Dr * axi + Di * axr + Cr * ayi + Ci_ * ayr;
                    xr[y] = Br * axr - Bi * axi + Ar * ayr - Ai * ayi;
                    xi[y] = Br * axi + Bi * axr + Ar * ayi + Ai * ayr;
                }
            }
        }

        #pragma unroll
        for (int v = 0; v < EL; ++v) {
            if constexpr (LAST) {
                st[boff + (gtb ^ pd.cl[CI].gcombo[v])] = make_float2(xr[v], xi[v]);
            } else {
                tile[ptb ^ pd.cl[CI].pcombo[v]] = make_float2(xr[v], xi[v]);
            }
        }
    }
}

template <int P>
__global__ __launch_bounds__(NT) void pass_kernel(float2* __restrict__ st,
        const float* __restrict__ utab,
        const float* __restrict__ in_re, const float* __restrict__ in_im) {
    constexpr PassDef pd = make_pass(P);
    __shared__ float2 tile[16384];
    unsigned bid = blockIdx.x;
    unsigned batch = bid >> 2;
    unsigned fr = bid & 3u;
    unsigned base = ((fr & 1u) << pd.fb0) | (((fr >> 1) & 1u) << pd.fb1);
    size_t boff = (size_t)batch << 16;

    do_cluster<P, 0>(tile, base, boff, st, utab, in_re, in_im);
    __syncthreads();
    do_cluster<P, 1>(tile, base, boff, st, utab, in_re, in_im);
    if constexpr (make_pass(P).nclust > 2) {
        __syncthreads();
        do_cluster<P, 2>(tile, base, boff, st, utab, in_re, in_im);
    }
}

extern "C" void kernel_launch(void* const* d_in, const int* in_sizes, int n_in,
                              void* d_out, int out_size, void* d_ws, size_t ws_size,
                              hipStream_t stream) {
    const float* in_re  = (const float*)d_in[0];
    const float* in_im  = (const float*)d_in[1];
    const float* params = (const float*)d_in[2];
    float2* st  = (float2*)d_out;
    float* utab = (float*)d_ws;      // 64 gates * 8 floats = 2 KB

    prep_gates<<<dim3(1), dim3(64), 0, stream>>>(params, utab);

    pass_kernel<0><<<dim3(1024), dim3(NT), 0, stream>>>(st, utab, in_re, in_im);
    pass_kernel<1><<<dim3(1024), dim3(NT), 0, stream>>>(st, utab, in_re, in_im);
    pass_kernel<2><<<dim3(1024), dim3(NT), 0, stream>>>(st, utab, in_re, in_im);
    pass_kernel<3><<<dim3(1024), dim3(NT), 0, stream>>>(st, utab, in_re, in_im);
    pass_kernel<4><<<dim3(1024), dim3(NT), 0, stream>>>(st, utab, in_re, in_im);
}

// Round 5
// 514.729 us; speedup vs baseline: 1.3337x; 1.3337x over previous
//
#include <hip/hip_runtime.h>
#include <hip/hip_fp16.h>
#include <math.h>

// PQC simulator: 16 qubits, 4 layers, batch 256.
// Storage index = FINAL logical index (CNOT-chain perms deferred & pre-composed):
//   storage[s] init = in[s ^ (s>>4)]
//   gate (t,q): pairs {s, s^m'}, m' = prefixXOR^(4-t)(e_q); role(s)=parity(w'&s)
// 5 passes, dim-14 tiles, 512 threads, register clusters of <=5 gates.
// State + LDS tile are packed fp16 (re|im<<16) -> 64KB tile, 2 blocks/CU.
// Compute stays fp32 in registers. Fallback to fp32-in-d_out if ws too small.

#define NT 512

constexpr unsigned mprime(int t, int q) {
    int u = 4 - t, b = 15 - q;
    unsigned m = 0;
    for (int s = 0; s <= b; ++s) {
        int n = u - 1 + s;
        if ((n & s) == s) m |= 1u << (b - s);   // Lucas: C(n,s) odd iff (n&s)==s
    }
    return m;
}
constexpr unsigned wprime(int t, int q) {
    int u = 4 - t, b = 15 - q;
    unsigned w = 0;
    for (int i = 0; b + i <= 15; ++i)
        if ((u & i) == i) w |= 1u << (b + i);
    return w;
}
constexpr int parity16(unsigned x) { int p = 0; for (int j = 0; j < 16; ++j) p ^= (int)((x >> j) & 1u); return p; }
constexpr int hibit(unsigned x) { int b = 0; for (int j = 0; j < 16; ++j) if ((x >> j) & 1u) b = j; return b; }
constexpr unsigned SWZc(unsigned l) { return l ^ ((l >> 4) & 0xFu) ^ ((l >> 8) & 0xFu) ^ ((l >> 12) & 0x3u); }

struct Cluster {
    int c;
    int gi[5];
    unsigned wglob[5], rho[5], lam[5];
    unsigned gcombo[32], pcombo[32];
    int np[14];
};
struct PassDef {
    int nclust;
    unsigned basis[14];
    int fb0, fb1;
    Cluster cl[3];
};

constexpr PassDef make_pass(int P) {
    PassDef pd{};
    int tq[14][2] = {}; int ng = 0;
    if (P == 0) { for (int q = 2; q <= 15; ++q) { tq[ng][0] = 0; tq[ng][1] = q; ++ng; } }
    if (P == 1) { tq[ng][0] = 0; tq[ng][1] = 0; ++ng; tq[ng][0] = 0; tq[ng][1] = 1; ++ng;
                  for (int q = 4; q <= 15; ++q) { tq[ng][0] = 1; tq[ng][1] = q; ++ng; } }
    if (P == 2) { for (int q = 0; q <= 3; ++q) { tq[ng][0] = 1; tq[ng][1] = q; ++ng; }
                  for (int q = 6; q <= 15; ++q) { tq[ng][0] = 2; tq[ng][1] = q; ++ng; } }
    if (P == 3) { for (int q = 0; q <= 5; ++q) { tq[ng][0] = 2; tq[ng][1] = q; ++ng; }
                  for (int q = 10; q <= 15; ++q) { tq[ng][0] = 3; tq[ng][1] = q; ++ng; } }
    if (P == 4) { for (int q = 0; q <= 9; ++q) { tq[ng][0] = 3; tq[ng][1] = q; ++ng; } }

    // basis (systematic: dense low bits + cleared-low residues with high pivots)
    if (P == 0) { for (int j = 0; j < 14; ++j) pd.basis[j] = 1u << j; pd.fb0 = 14; pd.fb1 = 15; }
    if (P == 1) { for (int j = 0; j < 12; ++j) pd.basis[j] = 1u << j;
                  pd.basis[12] = 1u << 14; pd.basis[13] = 1u << 15; pd.fb0 = 12; pd.fb1 = 13; }
    if (P == 2) { for (int j = 0; j < 10; ++j) pd.basis[j] = 1u << j;
                  pd.basis[10] = 0x1800u; pd.basis[11] = 0x3000u; pd.basis[12] = 0x6400u; pd.basis[13] = 0xCC00u;
                  pd.fb0 = 10; pd.fb1 = 11; }
    if (P == 3) { for (int j = 0; j < 8; ++j) pd.basis[j] = 1u << j;
                  pd.basis[8] = 0x0500u; pd.basis[9] = 0x0A00u; pd.basis[10] = 0x1500u;
                  pd.basis[11] = 0x2A00u; pd.basis[12] = 0x5500u; pd.basis[13] = 0xAA00u;
                  pd.fb0 = 8; pd.fb1 = 9; }
    if (P == 4) { for (int j = 0; j < 4; ++j) pd.basis[j] = 1u << j; pd.basis[4] = 0x70u;
                  for (int j = 5; j < 14; ++j) pd.basis[j] = 1u << (j + 2);
                  pd.fb0 = 4; pd.fb1 = 5; }

    // coverage check: basis pivots + free bits must tile all 16 positions
    {
        unsigned cov = (1u << pd.fb0) | (1u << pd.fb1);
        for (int j = 0; j < 14; ++j) cov |= 1u << hibit(pd.basis[j]);
        int chk = 1 / (cov == 0xFFFFu ? 1 : 0); (void)chk;
    }

    int csz[3] = {0, 0, 0}; int ncl = 3;
    if (P == 0 || P == 1 || P == 2) { csz[0] = 5; csz[1] = 5; csz[2] = 4; ncl = 3; }
    if (P == 3) { csz[0] = 5; csz[1] = 5; csz[2] = 2; ncl = 3; }
    if (P == 4) { csz[0] = 5; csz[1] = 5; ncl = 2; }
    pd.nclust = ncl;

    int bpiv[14] = {};
    for (int j = 0; j < 14; ++j) bpiv[j] = hibit(pd.basis[j]);

    int gpos = 0;
    for (int ci = 0; ci < ncl; ++ci) {
        Cluster& C = pd.cl[ci];
        C.c = csz[ci];
        unsigned mus[5] = {}, ms[5] = {};
        for (int g = 0; g < C.c; ++g) {
            int t = tq[gpos][0], q = tq[gpos][1]; ++gpos;
            C.gi[g] = t * 16 + q;
            unsigned m = mprime(t, q), w = wprime(t, q);
            ms[g] = m; C.wglob[g] = w;
            unsigned r = m, mu = 0;
            for (int pv = 15; pv >= 0; --pv) {
                if (!((r >> pv) & 1u)) continue;
                for (int j = 0; j < 14; ++j)
                    if (bpiv[j] == pv) { mu |= 1u << j; r ^= pd.basis[j]; break; }
            }
            mu = mu / (r == 0 ? 1u : 0u);           // trap: mask not in span
            unsigned rec = 0;
            for (int j = 0; j < 14; ++j) if ((mu >> j) & 1u) rec ^= pd.basis[j];
            int ver = 1 / (rec == m ? 1 : 0); (void)ver;  // trap: bad reduction
            mus[g] = mu;
            unsigned rho = 0;
            for (int j = 0; j < 14; ++j) rho |= (unsigned)parity16(w & pd.basis[j]) << j;
            C.rho[g] = rho;
        }
        for (int g = 0; g < C.c; ++g) {
            unsigned l = 0;
            for (int k = 0; k < C.c; ++k) l |= (unsigned)parity16(C.wglob[g] & ms[k]) << k;
            C.lam[g] = l;
        }
        unsigned pmask = 0;
        for (int g = 0; g < C.c; ++g) {
            int pv = hibit(mus[g]);
            int chk = 1 / (((pmask >> pv) & 1u) ? 0 : 1); (void)chk;  // trap: dup pivot
            pmask |= 1u << pv;
        }
        int nn = 0;
        for (int b = 0; b < 14; ++b) if (!((pmask >> b) & 1u)) C.np[nn++] = b;
        for (int v = 0; v < (1 << C.c); ++v) {
            unsigned wc = 0, gc = 0;
            for (int g = 0; g < C.c; ++g) if ((v >> g) & 1) { wc ^= mus[g]; gc ^= ms[g]; }
            C.gcombo[v] = gc; C.pcombo[v] = SWZc(wc);
        }
    }
    return pd;
}

// ---- prep: fuse RZ*RY*RX per (layer,qubit) into 8 floats ----
__global__ void prep_gates(const float* __restrict__ params, float* __restrict__ utab) {
    int i = threadIdx.x;
    if (i >= 64) return;
    int t = i >> 4, q = i & 15;
    float ax = params[(t * 16 + q) * 3 + 0];
    float ay = params[(t * 16 + q) * 3 + 1];
    float az = params[(t * 16 + q) * 3 + 2];
    float cx = cosf(0.5f * ax), sx = sinf(0.5f * ax);
    float cy = cosf(0.5f * ay), sy = sinf(0.5f * ay);
    float cz = cosf(0.5f * az), sz = sinf(0.5f * az);
    float A = cy * cx, B = sy * sx, C = sy * cx, D = cy * sx;
    float* o = utab + i * 8;
    o[0] = cz * A + sz * B;  o[1] = cz * B - sz * A;
    o[2] = -cz * C - sz * D; o[3] = sz * C - cz * D;
    o[4] = cz * C + sz * D;  o[5] = sz * C - cz * D;
    o[6] = cz * A + sz * B;  o[7] = sz * A - cz * B;
}

__device__ __forceinline__ float2 up16(unsigned u) {
    __half_raw h0; h0.x = (unsigned short)(u & 0xFFFFu);
    __half_raw h1; h1.x = (unsigned short)(u >> 16);
    return make_float2(__half2float(__half(h0)), __half2float(__half(h1)));
}
__device__ __forceinline__ unsigned dn16(float a, float b) {
    unsigned short ua = __half_as_ushort(__float2half_rn(a));
    unsigned short ub = __half_as_ushort(__float2half_rn(b));
    return (unsigned)ua | ((unsigned)ub << 16);
}

template <int P, int CI, bool H>
__device__ __forceinline__ void do_cluster(unsigned* __restrict__ tile16,
        float2* __restrict__ tile32,
        unsigned base, size_t boff,
        unsigned* __restrict__ st16, float2* __restrict__ st32,
        float2* __restrict__ out,
        const float* __restrict__ utab,
        const float* __restrict__ in_re, const float* __restrict__ in_im) {
    constexpr PassDef pd = make_pass(P);
    constexpr int CC = pd.cl[CI].c;
    constexpr int EL = 1 << CC;
    constexpr int NC = (1 << (14 - CC)) / NT;
    constexpr bool FIRST = (CI == 0);
    constexpr bool LAST = (CI + 1 == pd.nclust);
    constexpr bool FINAL = (P == 4) && LAST;   // fp32 float2 -> d_out

    #pragma unroll
    for (int cc = 0; cc < NC; ++cc) {
        unsigned idx = (unsigned)threadIdx.x + (unsigned)(cc * NT);
        unsigned tb = 0;
        #pragma unroll
        for (int i = 0; i < 14 - CC; ++i) tb |= ((idx >> i) & 1u) << pd.cl[CI].np[i];
        unsigned gtb = base;
        #pragma unroll
        for (int j = 0; j < 14; ++j) if ((tb >> j) & 1u) gtb ^= pd.basis[j];
        unsigned ptb = SWZc(tb);

        float xr[EL], xi[EL];
        #pragma unroll
        for (int v = 0; v < EL; ++v) {
            if constexpr (FIRST) {
                unsigned ga = gtb ^ pd.cl[CI].gcombo[v];
                if constexpr (P == 0) {
                    unsigned g4 = ga ^ (ga >> 4);      // gather absorbs final perm
                    xr[v] = in_re[boff + g4]; xi[v] = in_im[boff + g4];
                } else if constexpr (H) {
                    float2 f = up16(st16[boff + ga]); xr[v] = f.x; xi[v] = f.y;
                } else {
                    float2 f = st32[boff + ga]; xr[v] = f.x; xi[v] = f.y;
                }
            } else {
                unsigned pl = ptb ^ pd.cl[CI].pcombo[v];
                if constexpr (H) { float2 f = up16(tile16[pl]); xr[v] = f.x; xi[v] = f.y; }
                else             { float2 f = tile32[pl];       xr[v] = f.x; xi[v] = f.y; }
            }
        }

        #pragma unroll
        for (int g = 0; g < CC; ++g) {
            const float* u = utab + pd.cl[CI].gi[g] * 8;
            int r0 = (__popc(pd.cl[CI].rho[g] & tb) + __popc(pd.cl[CI].wglob[g] & base)) & 1;
            float u0r = u[0], u0i = u[1], u1r = u[2], u1i = u[3];
            float u2r = u[4], u2i = u[5], u3r = u[6], u3i = u[7];
            float Ar = r0 ? u3r : u0r, Ai = r0 ? u3i : u0i;
            float Br = r0 ? u2r : u1r, Bi = r0 ? u2i : u1i;
            float Cr = r0 ? u1r : u2r, Ci_ = r0 ? u1i : u2i;
            float Dr = r0 ? u0r : u3r, Di = r0 ? u0i : u3i;
            #pragma unroll
            for (int v = 0; v < EL; ++v) {
                if (v & (1 << g)) continue;
                int cpar = __popc(pd.cl[CI].lam[g] & (unsigned)v) & 1;   // folds
                int y = v | (1 << g);
                float axr = xr[v], axi = xi[v], ayr = xr[y], ayi = xi[y];
                if (cpar == 0) {
                    xr[v] = Ar * axr - Ai * axi + Br * ayr - Bi * ayi;
                    xi[v] = Ar * axi + Ai * axr + Br * ayi + Bi * ayr;
                    xr[y] = Cr * axr - Ci_ * axi + Dr * ayr - Di * ayi;
                    xi[y] = Cr * axi + Ci_ * axr + Dr * ayi + Di * ayr;
                } else {
                    xr[v] = Dr * axr - Di * axi + Cr * ayr - Ci_ * ayi;
                    xi[v] = Dr * axi + Di * axr + Cr * ayi + Ci_ * ayr;
                    xr[y] = Br * axr - Bi * axi + Ar * ayr - Ai * ayi;
                    xi[y] = Br * axi + Bi * axr + Ar * ayi + Ai * ayr;
                }
            }
        }

        #pragma unroll
        for (int v = 0; v < EL; ++v) {
            if constexpr (FINAL) {
                out[boff + (gtb ^ pd.cl[CI].gcombo[v])] = make_float2(xr[v], xi[v]);
            } else if constexpr (LAST) {
                unsigned ga = gtb ^ pd.cl[CI].gcombo[v];
                if constexpr (H) st16[boff + ga] = dn16(xr[v], xi[v]);
                else             st32[boff + ga] = make_float2(xr[v], xi[v]);
            } else {
                unsigned pl = ptb ^ pd.cl[CI].pcombo[v];
                if constexpr (H) tile16[pl] = dn16(xr[v], xi[v]);
                else             tile32[pl] = make_float2(xr[v], xi[v]);
            }
        }
    }
}

template <int P, bool H>
__global__ __launch_bounds__(NT) void pass_kernel(unsigned* __restrict__ st16,
        float2* __restrict__ st32, float2* __restrict__ out,
        const float* __restrict__ utab,
        const float* __restrict__ in_re, const float* __restrict__ in_im) {
    constexpr PassDef pd = make_pass(P);
    extern __shared__ unsigned char smem_raw[];
    unsigned* tile16 = reinterpret_cast<unsigned*>(smem_raw);
    float2*  tile32 = reinterpret_cast<float2*>(smem_raw);

    unsigned bid = blockIdx.x;
    unsigned batch = bid >> 2;
    unsigned fr = bid & 3u;
    unsigned base = ((fr & 1u) << pd.fb0) | (((fr >> 1) & 1u) << pd.fb1);
    size_t boff = (size_t)batch << 16;

    do_cluster<P, 0, H>(tile16, tile32, base, boff, st16, st32, out, utab, in_re, in_im);
    __syncthreads();
    do_cluster<P, 1, H>(tile16, tile32, base, boff, st16, st32, out, utab, in_re, in_im);
    if constexpr (make_pass(P).nclust > 2) {
        __syncthreads();
        do_cluster<P, 2, H>(tile16, tile32, base, boff, st16, st32, out, utab, in_re, in_im);
    }
}

extern "C" void kernel_launch(void* const* d_in, const int* in_sizes, int n_in,
                              void* d_out, int out_size, void* d_ws, size_t ws_size,
                              hipStream_t stream) {
    const float* in_re  = (const float*)d_in[0];
    const float* in_im  = (const float*)d_in[1];
    const float* params = (const float*)d_in[2];
    float2* out = (float2*)d_out;

    const size_t STATE_BYTES = 256ull * 65536ull * 4ull;   // packed fp16 state
    bool h = (ws_size >= STATE_BYTES + 4096);

    unsigned* st16 = (unsigned*)d_ws;
    float2*   st32 = out;                                  // fp32 fallback: in-place in d_out
    float* utab = h ? (float*)((char*)d_ws + STATE_BYTES) : (float*)d_ws;

    prep_gates<<<dim3(1), dim3(64), 0, stream>>>(params, utab);

    if (h) {
        const size_t SH = 16384 * 4;
        pass_kernel<0, true><<<dim3(1024), dim3(NT), SH, stream>>>(st16, st32, out, utab, in_re, in_im);
        pass_kernel<1, true><<<dim3(1024), dim3(NT), SH, stream>>>(st16, st32, out, utab, in_re, in_im);
        pass_kernel<2, true><<<dim3(1024), dim3(NT), SH, stream>>>(st16, st32, out, utab, in_re, in_im);
        pass_kernel<3, true><<<dim3(1024), dim3(NT), SH, stream>>>(st16, st32, out, utab, in_re, in_im);
        pass_kernel<4, true><<<dim3(1024), dim3(NT), SH, stream>>>(st16, st32, out, utab, in_re, in_im);
    } else {
        const size_t SH = 16384 * 8;
        pass_kernel<0, false><<<dim3(1024), dim3(NT), SH, stream>>>(st16, st32, out, utab, in_re, in_im);
        pass_kernel<1, false><<<dim3(1024), dim3(NT), SH, stream>>>(st16, st32, out, utab, in_re, in_im);
        pass_kernel<2, false><<<dim3(1024), dim3(NT), SH, stream>>>(st16, st32, out, utab, in_re, in_im);
        pass_kernel<3, false><<<dim3(1024), dim3(NT), SH, stream>>>(st16, st32, out, utab, in_re, in_im);
        pass_kernel<4, false><<<dim3(1024), dim3(NT), SH, stream>>>(st16, st32, out, utab, in_re, in_im);
    }
}

// Round 7
// 446.829 us; speedup vs baseline: 1.5364x; 1.1520x over previous
//
#include <hip/hip_runtime.h>
#include <hip/hip_fp16.h>
#include <math.h>

// PQC simulator: 16 qubits, 4 layers, batch 256.
// Storage index = FINAL logical index (CNOT-chain perms deferred & pre-composed):
//   storage[s] init = in[s ^ (s>>4)]
//   gate (t,q): pairs {s, s^m'}, m' = prefixXOR^(4-t)(e_q); role(s)=parity(w'&s)
// 5 passes, dim-14 tiles, 512 threads, register clusters of <=5 gates.
// Linear LDS staging both ends -> every global access coalesced; clusters are
// LDS-only. NSWZ preserves bit0 (b64 staging), mixes coords 4..13 into bank
// bits 1..4. State fp16-packed in d_ws; compute fp32; fp32 fallback.
// r7 fix: P0 stage-in loads ALIGNED 4-group (g4 & ~3) and applies the
// gray-twist's intra-group XOR permutation via predicated swaps (the
// misaligned float4 at g4 was the r6 fault).

#define NT 512

constexpr unsigned mprime(int t, int q) {
    int u = 4 - t, b = 15 - q;
    unsigned m = 0;
    for (int s = 0; s <= b; ++s) {
        int n = u - 1 + s;
        if ((n & s) == s) m |= 1u << (b - s);   // Lucas: C(n,s) odd iff (n&s)==s
    }
    return m;
}
constexpr unsigned wprime(int t, int q) {
    int u = 4 - t, b = 15 - q;
    unsigned w = 0;
    for (int i = 0; b + i <= 15; ++i)
        if ((u & i) == i) w |= 1u << (b + i);
    return w;
}
constexpr int parity16(unsigned x) { int p = 0; for (int j = 0; j < 16; ++j) p ^= (int)((x >> j) & 1u); return p; }
constexpr int hibit(unsigned x) { int b = 0; for (int j = 0; j < 16; ++j) if ((x >> j) & 1u) b = j; return b; }
// swizzle: XOR nibble-fold of bits 4..13 into bits 1..4; preserves bit 0.
constexpr unsigned NSWZ(unsigned l) {
    unsigned b = ((l >> 4) & 0xFu) ^ ((l >> 8) & 0xFu) ^ ((l >> 12) & 0xFu);
    return l ^ (b << 1);
}

struct Cluster {
    int c;
    int gi[5];
    unsigned wglob[5], rho[5], lam[5];
    unsigned pcombo[32];
    int np[14];
};
struct PassDef {
    int nclust;
    unsigned basis[14];
    int fb0, fb1;
    Cluster cl[3];
};

constexpr PassDef make_pass(int P) {
    PassDef pd{};
    int tq[14][2] = {}; int ng = 0;
    if (P == 0) { for (int q = 2; q <= 15; ++q) { tq[ng][0] = 0; tq[ng][1] = q; ++ng; } }
    if (P == 1) { tq[ng][0] = 0; tq[ng][1] = 0; ++ng; tq[ng][0] = 0; tq[ng][1] = 1; ++ng;
                  for (int q = 4; q <= 15; ++q) { tq[ng][0] = 1; tq[ng][1] = q; ++ng; } }
    if (P == 2) { for (int q = 0; q <= 3; ++q) { tq[ng][0] = 1; tq[ng][1] = q; ++ng; }
                  for (int q = 6; q <= 15; ++q) { tq[ng][0] = 2; tq[ng][1] = q; ++ng; } }
    if (P == 3) { for (int q = 0; q <= 5; ++q) { tq[ng][0] = 2; tq[ng][1] = q; ++ng; }
                  for (int q = 10; q <= 15; ++q) { tq[ng][0] = 3; tq[ng][1] = q; ++ng; } }
    if (P == 4) { for (int q = 0; q <= 9; ++q) { tq[ng][0] = 3; tq[ng][1] = q; ++ng; } }

    // basis (systematic: dense low bits + cleared-low residues with high pivots)
    if (P == 0) { for (int j = 0; j < 14; ++j) pd.basis[j] = 1u << j; pd.fb0 = 14; pd.fb1 = 15; }
    if (P == 1) { for (int j = 0; j < 12; ++j) pd.basis[j] = 1u << j;
                  pd.basis[12] = 1u << 14; pd.basis[13] = 1u << 15; pd.fb0 = 12; pd.fb1 = 13; }
    if (P == 2) { for (int j = 0; j < 10; ++j) pd.basis[j] = 1u << j;
                  pd.basis[10] = 0x1800u; pd.basis[11] = 0x3000u; pd.basis[12] = 0x6400u; pd.basis[13] = 0xCC00u;
                  pd.fb0 = 10; pd.fb1 = 11; }
    if (P == 3) { for (int j = 0; j < 8; ++j) pd.basis[j] = 1u << j;
                  pd.basis[8] = 0x0500u; pd.basis[9] = 0x0A00u; pd.basis[10] = 0x1500u;
                  pd.basis[11] = 0x2A00u; pd.basis[12] = 0x5500u; pd.basis[13] = 0xAA00u;
                  pd.fb0 = 8; pd.fb1 = 9; }
    if (P == 4) { for (int j = 0; j < 4; ++j) pd.basis[j] = 1u << j; pd.basis[4] = 0x70u;
                  for (int j = 5; j < 14; ++j) pd.basis[j] = 1u << (j + 2);
                  pd.fb0 = 4; pd.fb1 = 5; }

    // coverage check: basis pivots + free bits must tile all 16 positions
    {
        unsigned cov = (1u << pd.fb0) | (1u << pd.fb1);
        for (int j = 0; j < 14; ++j) cov |= 1u << hibit(pd.basis[j]);
        int chk = 1 / (cov == 0xFFFFu ? 1 : 0); (void)chk;
    }

    int csz[3] = {0, 0, 0}; int ncl = 3;
    if (P == 0 || P == 1 || P == 2) { csz[0] = 5; csz[1] = 5; csz[2] = 4; ncl = 3; }
    if (P == 3) { csz[0] = 5; csz[1] = 5; csz[2] = 2; ncl = 3; }
    if (P == 4) { csz[0] = 5; csz[1] = 5; ncl = 2; }
    pd.nclust = ncl;

    int bpiv[14] = {};
    for (int j = 0; j < 14; ++j) bpiv[j] = hibit(pd.basis[j]);

    int gpos = 0;
    for (int ci = 0; ci < ncl; ++ci) {
        Cluster& C = pd.cl[ci];
        C.c = csz[ci];
        unsigned mus[5] = {}, ms[5] = {};
        for (int g = 0; g < C.c; ++g) {
            int t = tq[gpos][0], q = tq[gpos][1]; ++gpos;
            C.gi[g] = t * 16 + q;
            unsigned m = mprime(t, q), w = wprime(t, q);
            ms[g] = m; C.wglob[g] = w;
            unsigned r = m, mu = 0;
            for (int pv = 15; pv >= 0; --pv) {
                if (!((r >> pv) & 1u)) continue;
                for (int j = 0; j < 14; ++j)
                    if (bpiv[j] == pv) { mu |= 1u << j; r ^= pd.basis[j]; break; }
            }
            mu = mu / (r == 0 ? 1u : 0u);           // trap: mask not in span
            unsigned rec = 0;
            for (int j = 0; j < 14; ++j) if ((mu >> j) & 1u) rec ^= pd.basis[j];
            int ver = 1 / (rec == m ? 1 : 0); (void)ver;  // trap: bad reduction
            mus[g] = mu;
            unsigned rho = 0;
            for (int j = 0; j < 14; ++j) rho |= (unsigned)parity16(w & pd.basis[j]) << j;
            C.rho[g] = rho;
        }
        for (int g = 0; g < C.c; ++g) {
            unsigned l = 0;
            for (int k = 0; k < C.c; ++k) l |= (unsigned)parity16(C.wglob[g] & ms[k]) << k;
            C.lam[g] = l;
        }
        unsigned pmask = 0;
        for (int g = 0; g < C.c; ++g) {
            int pv = hibit(mus[g]);
            int chk = 1 / (((pmask >> pv) & 1u) ? 0 : 1); (void)chk;  // trap: dup pivot
            pmask |= 1u << pv;
        }
        int nn = 0;
        for (int b = 0; b < 14; ++b) if (!((pmask >> b) & 1u)) C.np[nn++] = b;
        for (int v = 0; v < (1 << C.c); ++v) {
            unsigned wc = 0;
            for (int g = 0; g < C.c; ++g) if ((v >> g) & 1) wc ^= mus[g];
            C.pcombo[v] = NSWZ(wc);
        }
    }
    return pd;
}

// ---- prep: fuse RZ*RY*RX per (layer,qubit) into 8 floats ----
__global__ void prep_gates(const float* __restrict__ params, float* __restrict__ utab) {
    int i = threadIdx.x;
    if (i >= 64) return;
    int t = i >> 4, q = i & 15;
    float ax = params[(t * 16 + q) * 3 + 0];
    float ay = params[(t * 16 + q) * 3 + 1];
    float az = params[(t * 16 + q) * 3 + 2];
    float cx = cosf(0.5f * ax), sx = sinf(0.5f * ax);
    float cy = cosf(0.5f * ay), sy = sinf(0.5f * ay);
    float cz = cosf(0.5f * az), sz = sinf(0.5f * az);
    float A = cy * cx, B = sy * sx, C = sy * cx, D = cy * sx;
    float* o = utab + i * 8;
    o[0] = cz * A + sz * B;  o[1] = cz * B - sz * A;
    o[2] = -cz * C - sz * D; o[3] = sz * C - cz * D;
    o[4] = cz * C + sz * D;  o[5] = sz * C - cz * D;
    o[6] = cz * A + sz * B;  o[7] = sz * A - cz * B;
}

__device__ __forceinline__ float2 up16(unsigned u) {
    __half_raw h0; h0.x = (unsigned short)(u & 0xFFFFu);
    __half_raw h1; h1.x = (unsigned short)(u >> 16);
    return make_float2(__half2float(__half(h0)), __half2float(__half(h1)));
}
__device__ __forceinline__ unsigned dn16(float a, float b) {
    unsigned short ua = __half_as_ushort(__float2half_rn(a));
    unsigned short ub = __half_as_ushort(__float2half_rn(b));
    return (unsigned)ua | ((unsigned)ub << 16);
}

// ---- linear staging: global <-> LDS, fully coalesced ----
template <int P, bool H>
__device__ __forceinline__ void stage_in(unsigned* __restrict__ tile16,
        float2* __restrict__ tile32, unsigned base, size_t boff,
        const unsigned* __restrict__ st16, const float2* __restrict__ st32,
        const float* __restrict__ in_re, const float* __restrict__ in_im) {
    constexpr PassDef pd = make_pass(P);
    #pragma unroll
    for (int it = 0; it < 16384 / (4 * NT); ++it) {
        unsigned i = 4u * ((unsigned)threadIdx.x + (unsigned)(it * NT));
        unsigned gtb = base;
        #pragma unroll
        for (int j = 2; j < 14; ++j) if ((i >> j) & 1u) gtb ^= pd.basis[j];
        unsigned sa = NSWZ(i);                  // bit0=0; {sa,sa^1},{sa^2,sa^3} are b64 pairs
        if constexpr (P == 0) {
            // gray-twist maps the aligned 4-group at gtb to the aligned group
            // at (g4 & ~3) with intra-group XOR perm k -> k^lo. Load aligned,
            // permute in registers (predicated swaps; no misaligned vec load).
            unsigned g4 = gtb ^ (gtb >> 4);
            unsigned gb = g4 & ~3u;
            unsigned lo = g4 & 3u;
            float4 vr = *(const float4*)(in_re + boff + gb);
            float4 vi = *(const float4*)(in_im + boff + gb);
            float r0 = vr.x, r1 = vr.y, r2 = vr.z, r3 = vr.w;
            float i0 = vi.x, i1 = vi.y, i2 = vi.z, i3 = vi.w;
            if (lo & 1u) { float t;
                t = r0; r0 = r1; r1 = t;  t = r2; r2 = r3; r3 = t;
                t = i0; i0 = i1; i1 = t;  t = i2; i2 = i3; i3 = t; }
            if (lo & 2u) { float t;
                t = r0; r0 = r2; r2 = t;  t = r1; r1 = r3; r3 = t;
                t = i0; i0 = i2; i2 = t;  t = i1; i1 = i3; i3 = t; }
            // slot k (lds sa^k) now holds orig[k ^ lo]
            if constexpr (H) {
                *(uint2*)&tile16[sa]     = make_uint2(dn16(r0, i0), dn16(r1, i1));
                *(uint2*)&tile16[sa ^ 2] = make_uint2(dn16(r2, i2), dn16(r3, i3));
            } else {
                *(float4*)&tile32[sa]     = make_float4(r0, i0, r1, i1);
                *(float4*)&tile32[sa ^ 2] = make_float4(r2, i2, r3, i3);
            }
        } else if constexpr (H) {
            uint4 v = *(const uint4*)(st16 + boff + gtb);
            *(uint2*)&tile16[sa]     = make_uint2(v.x, v.y);
            *(uint2*)&tile16[sa ^ 2] = make_uint2(v.z, v.w);
        } else {
            float4 a = *(const float4*)(st32 + boff + gtb);
            float4 b = *(const float4*)(st32 + boff + gtb + 2);
            *(float4*)&tile32[sa]     = a;
            *(float4*)&tile32[sa ^ 2] = b;
        }
    }
}

template <int P, bool H>
__device__ __forceinline__ void stage_out(const unsigned* __restrict__ tile16,
        const float2* __restrict__ tile32, unsigned base, size_t boff,
        unsigned* __restrict__ st16, float2* __restrict__ st32,
        float2* __restrict__ out) {
    constexpr PassDef pd = make_pass(P);
    #pragma unroll
    for (int it = 0; it < 16384 / (4 * NT); ++it) {
        unsigned i = 4u * ((unsigned)threadIdx.x + (unsigned)(it * NT));
        unsigned gtb = base;
        #pragma unroll
        for (int j = 2; j < 14; ++j) if ((i >> j) & 1u) gtb ^= pd.basis[j];
        unsigned sa = NSWZ(i);
        if constexpr (H) {
            uint2 a = *(const uint2*)&tile16[sa];
            uint2 b = *(const uint2*)&tile16[sa ^ 2];
            if constexpr (P == 4) {
                float2 f0 = up16(a.x), f1 = up16(a.y), f2 = up16(b.x), f3 = up16(b.y);
                *(float4*)&out[boff + gtb]     = make_float4(f0.x, f0.y, f1.x, f1.y);
                *(float4*)&out[boff + gtb + 2] = make_float4(f2.x, f2.y, f3.x, f3.y);
            } else {
                *(uint4*)(st16 + boff + gtb) = make_uint4(a.x, a.y, b.x, b.y);
            }
        } else {
            float4 a = *(const float4*)&tile32[sa];
            float4 b = *(const float4*)&tile32[sa ^ 2];
            float2* dst = (P == 4) ? out : st32;
            *(float4*)&dst[boff + gtb]     = a;
            *(float4*)&dst[boff + gtb + 2] = b;
        }
    }
}

template <int P, int CI, bool H>
__device__ __forceinline__ void do_cluster(unsigned* __restrict__ tile16,
        float2* __restrict__ tile32, unsigned base,
        const float* __restrict__ utab) {
    constexpr PassDef pd = make_pass(P);
    constexpr int CC = pd.cl[CI].c;
    constexpr int EL = 1 << CC;
    constexpr int NC = (1 << (14 - CC)) / NT;

    #pragma unroll
    for (int cc = 0; cc < NC; ++cc) {
        unsigned idx = (unsigned)threadIdx.x + (unsigned)(cc * NT);
        unsigned tb = 0;
        #pragma unroll
        for (int i = 0; i < 14 - CC; ++i) tb |= ((idx >> i) & 1u) << pd.cl[CI].np[i];
        unsigned ptb = NSWZ(tb);

        float xr[EL], xi[EL];
        #pragma unroll
        for (int v = 0; v < EL; ++v) {
            unsigned pl = ptb ^ pd.cl[CI].pcombo[v];
            if constexpr (H) { float2 f = up16(tile16[pl]); xr[v] = f.x; xi[v] = f.y; }
            else             { float2 f = tile32[pl];       xr[v] = f.x; xi[v] = f.y; }
        }

        #pragma unroll
        for (int g = 0; g < CC; ++g) {
            const float* u = utab + pd.cl[CI].gi[g] * 8;
            int r0 = (__popc(pd.cl[CI].rho[g] & tb) + __popc(pd.cl[CI].wglob[g] & base)) & 1;
            float u0r = u[0], u0i = u[1], u1r = u[2], u1i = u[3];
            float u2r = u[4], u2i = u[5], u3r = u[6], u3i = u[7];
            float Ar = r0 ? u3r : u0r, Ai = r0 ? u3i : u0i;
            float Br = r0 ? u2r : u1r, Bi = r0 ? u2i : u1i;
            float Cr = r0 ? u1r : u2r, Ci_ = r0 ? u1i : u2i;
            float Dr = r0 ? u0r : u3r, Di = r0 ? u0i : u3i;
            #pragma unroll
            for (int v = 0; v < EL; ++v) {
                if (v & (1 << g)) continue;
                int cpar = __popc(pd.cl[CI].lam[g] & (unsigned)v) & 1;   // folds
                int y = v | (1 << g);
                float axr = xr[v], axi = xi[v], ayr = xr[y], ayi = xi[y];
                if (cpar == 0) {
                    xr[v] = Ar * axr - Ai * axi + Br * ayr - Bi * ayi;
                    xi[v] = Ar * axi + Ai * axr + Br * ayi + Bi * ayr;
                    xr[y] = Cr * axr - Ci_ * axi + Dr * ayr - Di * ayi;
                    xi[y] = Cr * axi + Ci_ * axr + Dr * ayi + Di * ayr;
                } else {
                    xr[v] = Dr * axr - Di * axi + Cr * ayr - Ci_ * ayi;
                    xi[v] = Dr * axi + Di * axr + Cr * ayi + Ci_ * ayr;
                    xr[y] = Br * axr - Bi * axi + Ar * ayr - Ai * ayi;
                    xi[y] = Br * axi + Bi * axr + Ar * ayi + Ai * ayr;
                }
            }
        }

        #pragma unroll
        for (int v = 0; v < EL; ++v) {
            unsigned pl = ptb ^ pd.cl[CI].pcombo[v];
            if constexpr (H) tile16[pl] = dn16(xr[v], xi[v]);
            else             tile32[pl] = make_float2(xr[v], xi[v]);
        }
    }
}

template <int P, bool H>
__global__ __launch_bounds__(NT) void pass_kernel(unsigned* __restrict__ st16,
        float2* __restrict__ st32, float2* __restrict__ out,
        const float* __restrict__ utab,
        const float* __restrict__ in_re, const float* __restrict__ in_im) {
    extern __shared__ unsigned char smem_raw[];
    unsigned* tile16 = reinterpret_cast<unsigned*>(smem_raw);
    float2*  tile32 = reinterpret_cast<float2*>(smem_raw);
    constexpr PassDef pd = make_pass(P);

    unsigned bid = blockIdx.x;
    unsigned batch = bid >> 2;
    unsigned fr = bid & 3u;
    unsigned base = ((fr & 1u) << pd.fb0) | (((fr >> 1) & 1u) << pd.fb1);
    size_t boff = (size_t)batch << 16;

    stage_in<P, H>(tile16, tile32, base, boff, st16, st32, in_re, in_im);
    __syncthreads();
    do_cluster<P, 0, H>(tile16, tile32, base, utab);
    __syncthreads();
    do_cluster<P, 1, H>(tile16, tile32, base, utab);
    __syncthreads();
    if constexpr (make_pass(P).nclust > 2) {
        do_cluster<P, 2, H>(tile16, tile32, base, utab);
        __syncthreads();
    }
    stage_out<P, H>(tile16, tile32, base, boff, st16, st32, out);
}

extern "C" void kernel_launch(void* const* d_in, const int* in_sizes, int n_in,
                              void* d_out, int out_size, void* d_ws, size_t ws_size,
                              hipStream_t stream) {
    const float* in_re  = (const float*)d_in[0];
    const float* in_im  = (const float*)d_in[1];
    const float* params = (const float*)d_in[2];
    float2* out = (float2*)d_out;

    const size_t STATE_BYTES = 256ull * 65536ull * 4ull;   // packed fp16 state
    bool h = (ws_size >= STATE_BYTES + 4096);

    unsigned* st16 = (unsigned*)d_ws;
    float2*   st32 = out;                                  // fp32 fallback: in-place in d_out
    float* utab = h ? (float*)((char*)d_ws + STATE_BYTES) : (float*)d_ws;

    prep_gates<<<dim3(1), dim3(64), 0, stream>>>(params, utab);

    if (h) {
        const size_t SH = 16384 * 4;
        pass_kernel<0, true><<<dim3(1024), dim3(NT), SH, stream>>>(st16, st32, out, utab, in_re, in_im);
        pass_kernel<1, true><<<dim3(1024), dim3(NT), SH, stream>>>(st16, st32, out, utab, in_re, in_im);
        pass_kernel<2, true><<<dim3(1024), dim3(NT), SH, stream>>>(st16, st32, out, utab, in_re, in_im);
        pass_kernel<3, true><<<dim3(1024), dim3(NT), SH, stream>>>(st16, st32, out, utab, in_re, in_im);
        pass_kernel<4, true><<<dim3(1024), dim3(NT), SH, stream>>>(st16, st32, out, utab, in_re, in_im);
    } else {
        const size_t SH = 16384 * 8;
        pass_kernel<0, false><<<dim3(1024), dim3(NT), SH, stream>>>(st16, st32, out, utab, in_re, in_im);
        pass_kernel<1, false><<<dim3(1024), dim3(NT), SH, stream>>>(st16, st32, out, utab, in_re, in_im);
        pass_kernel<2, false><<<dim3(1024), dim3(NT), SH, stream>>>(st16, st32, out, utab, in_re, in_im);
        pass_kernel<3, false><<<dim3(1024), dim3(NT), SH, stream>>>(st16, st32, out, utab, in_re, in_im);
        pass_kernel<4, false><<<dim3(1024), dim3(NT), SH, stream>>>(st16, st32, out, utab, in_re, in_im);
    }
}

// Round 8
// 243.938 us; speedup vs baseline: 2.8143x; 1.8317x over previous
//
#include <hip/hip_runtime.h>
#include <hip/hip_fp16.h>
#include <math.h>

// PQC simulator: 16 qubits, 4 layers, batch 256.
// Storage index = FINAL logical index (CNOT perms deferred & pre-composed):
//   storage[s] init = in[s ^ (s>>4)]
//   gate (t,q): pairs {s, s^m'}, m' = prefixXOR^(4-t)(e_q); role(s)=parity(w'&s)
// 5 passes, dim-14 tiles, 512 threads. Linear LDS staging (coalesced global).
// r8: clusters are MFMA matmuls. Each cluster = fixed 32x32 (CC=5) or 16x16
// (CC=4) complex matrix built once by build_mats. Per-coset role pattern p is
// absorbed by XOR-shifting addresses with pcombo[Linv p] (Lambda = lam table,
// unit-lower-triangular => invertible; pst[] = precomputed pcombo[Linv e_k]).
// State fp16-packed in d_ws; compute fp32 accum; fp32 scalar fallback.

#define NT 512

typedef __attribute__((ext_vector_type(8))) _Float16 half8_t;
typedef __attribute__((ext_vector_type(16))) float f32x16_t;
typedef __attribute__((ext_vector_type(4))) float f32x4_t;

constexpr unsigned mprime(int t, int q) {
    int u = 4 - t, b = 15 - q;
    unsigned m = 0;
    for (int s = 0; s <= b; ++s) {
        int n = u - 1 + s;
        if ((n & s) == s) m |= 1u << (b - s);   // Lucas: C(n,s) odd iff (n&s)==s
    }
    return m;
}
constexpr unsigned wprime(int t, int q) {
    int u = 4 - t, b = 15 - q;
    unsigned w = 0;
    for (int i = 0; b + i <= 15; ++i)
        if ((u & i) == i) w |= 1u << (b + i);
    return w;
}
constexpr int parity16(unsigned x) { int p = 0; for (int j = 0; j < 16; ++j) p ^= (int)((x >> j) & 1u); return p; }
constexpr int hibit(unsigned x) { int b = 0; for (int j = 0; j < 16; ++j) if ((x >> j) & 1u) b = j; return b; }
// swizzle: XOR nibble-fold of bits 4..13 into bits 1..4; preserves bit 0.
constexpr unsigned NSWZ(unsigned l) {
    unsigned b = ((l >> 4) & 0xFu) ^ ((l >> 8) & 0xFu) ^ ((l >> 12) & 0xFu);
    return l ^ (b << 1);
}

struct Cluster {
    int c;
    int gi[5];
    unsigned wglob[5], rho[5], lam[5], pst[5];
    unsigned pcombo[32];
    int np[14];
};
struct PassDef {
    int nclust;
    unsigned basis[14];
    int fb0, fb1;
    Cluster cl[3];
};

constexpr PassDef make_pass(int P) {
    PassDef pd{};
    int tq[14][2] = {}; int ng = 0;
    if (P == 0) { for (int q = 2; q <= 15; ++q) { tq[ng][0] = 0; tq[ng][1] = q; ++ng; } }
    if (P == 1) { tq[ng][0] = 0; tq[ng][1] = 0; ++ng; tq[ng][0] = 0; tq[ng][1] = 1; ++ng;
                  for (int q = 4; q <= 15; ++q) { tq[ng][0] = 1; tq[ng][1] = q; ++ng; } }
    if (P == 2) { for (int q = 0; q <= 3; ++q) { tq[ng][0] = 1; tq[ng][1] = q; ++ng; }
                  for (int q = 6; q <= 15; ++q) { tq[ng][0] = 2; tq[ng][1] = q; ++ng; } }
    if (P == 3) { for (int q = 0; q <= 5; ++q) { tq[ng][0] = 2; tq[ng][1] = q; ++ng; }
                  for (int q = 10; q <= 15; ++q) { tq[ng][0] = 3; tq[ng][1] = q; ++ng; } }
    if (P == 4) { for (int q = 0; q <= 9; ++q) { tq[ng][0] = 3; tq[ng][1] = q; ++ng; } }

    if (P == 0) { for (int j = 0; j < 14; ++j) pd.basis[j] = 1u << j; pd.fb0 = 14; pd.fb1 = 15; }
    if (P == 1) { for (int j = 0; j < 12; ++j) pd.basis[j] = 1u << j;
                  pd.basis[12] = 1u << 14; pd.basis[13] = 1u << 15; pd.fb0 = 12; pd.fb1 = 13; }
    if (P == 2) { for (int j = 0; j < 10; ++j) pd.basis[j] = 1u << j;
                  pd.basis[10] = 0x1800u; pd.basis[11] = 0x3000u; pd.basis[12] = 0x6400u; pd.basis[13] = 0xCC00u;
                  pd.fb0 = 10; pd.fb1 = 11; }
    if (P == 3) { for (int j = 0; j < 8; ++j) pd.basis[j] = 1u << j;
                  pd.basis[8] = 0x0500u; pd.basis[9] = 0x0A00u; pd.basis[10] = 0x1500u;
                  pd.basis[11] = 0x2A00u; pd.basis[12] = 0x5500u; pd.basis[13] = 0xAA00u;
                  pd.fb0 = 8; pd.fb1 = 9; }
    if (P == 4) { for (int j = 0; j < 4; ++j) pd.basis[j] = 1u << j; pd.basis[4] = 0x70u;
                  for (int j = 5; j < 14; ++j) pd.basis[j] = 1u << (j + 2);
                  pd.fb0 = 4; pd.fb1 = 5; }

    {   // coverage check: basis pivots + free bits tile all 16 positions
        unsigned cov = (1u << pd.fb0) | (1u << pd.fb1);
        for (int j = 0; j < 14; ++j) cov |= 1u << hibit(pd.basis[j]);
        int chk = 1 / (cov == 0xFFFFu ? 1 : 0); (void)chk;
    }

    int csz[3] = {0, 0, 0}; int ncl = 3;
    if (P == 0 || P == 1 || P == 2) { csz[0] = 5; csz[1] = 5; csz[2] = 4; ncl = 3; }
    if (P == 3) { csz[0] = 4; csz[1] = 4; csz[2] = 4; ncl = 3; }
    if (P == 4) { csz[0] = 5; csz[1] = 5; ncl = 2; }
    pd.nclust = ncl;

    int bpiv[14] = {};
    for (int j = 0; j < 14; ++j) bpiv[j] = hibit(pd.basis[j]);

    int gpos = 0;
    for (int ci = 0; ci < ncl; ++ci) {
        Cluster& C = pd.cl[ci];
        C.c = csz[ci];
        unsigned mus[5] = {}, ms[5] = {};
        for (int g = 0; g < C.c; ++g) {
            int t = tq[gpos][0], q = tq[gpos][1]; ++gpos;
            C.gi[g] = t * 16 + q;
            unsigned m = mprime(t, q), w = wprime(t, q);
            ms[g] = m; C.wglob[g] = w;
            unsigned r = m, mu = 0;
            for (int pv = 15; pv >= 0; --pv) {
                if (!((r >> pv) & 1u)) continue;
                for (int j = 0; j < 14; ++j)
                    if (bpiv[j] == pv) { mu |= 1u << j; r ^= pd.basis[j]; break; }
            }
            mu = mu / (r == 0 ? 1u : 0u);           // trap: mask not in span
            unsigned rec = 0;
            for (int j = 0; j < 14; ++j) if ((mu >> j) & 1u) rec ^= pd.basis[j];
            int ver = 1 / (rec == m ? 1 : 0); (void)ver;
            mus[g] = mu;
            unsigned rho = 0;
            for (int j = 0; j < 14; ++j) rho |= (unsigned)parity16(w & pd.basis[j]) << j;
            C.rho[g] = rho;
        }
        for (int g = 0; g < C.c; ++g) {
            unsigned l = 0;
            for (int k = 0; k < C.c; ++k) l |= (unsigned)parity16(C.wglob[g] & ms[k]) << k;
            C.lam[g] = l;
            int tri = 1 / ((l >> (g + 1)) == 0u ? 1 : 0); (void)tri;   // trap: Lambda not lower-tri
        }
        unsigned pmask = 0;
        for (int g = 0; g < C.c; ++g) {
            int pv = hibit(mus[g]);
            int chk = 1 / (((pmask >> pv) & 1u) ? 0 : 1); (void)chk;   // trap: dup pivot
            pmask |= 1u << pv;
        }
        int nn = 0;
        for (int b = 0; b < 14; ++b) if (!((pmask >> b) & 1u)) C.np[nn++] = b;
        for (int v = 0; v < (1 << C.c); ++v) {
            unsigned wc = 0;
            for (int g = 0; g < C.c; ++g) if ((v >> g) & 1) wc ^= mus[g];
            C.pcombo[v] = NSWZ(wc);
        }
        // pst[k] = pcombo[Linv e_k]  (forward substitution on unit-lower-tri lam)
        for (int k = 0; k < C.c; ++k) {
            unsigned m = 0;
            for (int g = 0; g < C.c; ++g) {
                unsigned pg = (k == g) ? 1u : 0u;
                unsigned lamlow = C.lam[g] & ((1u << g) - 1u);
                unsigned mg = pg ^ (unsigned)parity16(lamlow & m);
                m |= mg << g;
            }
            C.pst[k] = C.pcombo[m];
        }
    }
    return pd;
}

// ---- build descriptors for the matrix-build kernel (runtime-indexed) ----
struct BuildDesc { int cc; int gi[5]; unsigned lam[5]; };
constexpr BuildDesc mkbd(int cid) {
    int P = (cid < 12) ? cid / 3 : 4;
    int CI = (cid < 12) ? cid % 3 : cid - 12;
    PassDef pd = make_pass(P);
    BuildDesc b{};
    b.cc = pd.cl[CI].c;
    for (int g = 0; g < 5; ++g) { b.gi[g] = pd.cl[CI].gi[g]; b.lam[g] = pd.cl[CI].lam[g]; }
    return b;
}
constexpr BuildDesc BD[14] = {
    mkbd(0), mkbd(1), mkbd(2), mkbd(3), mkbd(4), mkbd(5), mkbd(6),
    mkbd(7), mkbd(8), mkbd(9), mkbd(10), mkbd(11), mkbd(12), mkbd(13)
};

// ---- prep: fuse RZ*RY*RX per (layer,qubit) into 8 floats ----
__global__ void prep_gates(const float* __restrict__ params, float* __restrict__ utab) {
    int i = threadIdx.x;
    if (i >= 64) return;
    int t = i >> 4, q = i & 15;
    float ax = params[(t * 16 + q) * 3 + 0];
    float ay = params[(t * 16 + q) * 3 + 1];
    float az = params[(t * 16 + q) * 3 + 2];
    float cx = cosf(0.5f * ax), sx = sinf(0.5f * ax);
    float cy = cosf(0.5f * ay), sy = sinf(0.5f * ay);
    float cz = cosf(0.5f * az), sz = sinf(0.5f * az);
    float A = cy * cx, B = sy * sx, C = sy * cx, D = cy * sx;
    float* o = utab + i * 8;
    o[0] = cz * A + sz * B;  o[1] = cz * B - sz * A;
    o[2] = -cz * C - sz * D; o[3] = sz * C - cz * D;
    o[4] = cz * C + sz * D;  o[5] = sz * C - cz * D;
    o[6] = cz * A + sz * B;  o[7] = sz * A - cz * B;
}

// ---- build per-cluster matrices (pattern-0 baseline), f16, padded 32x32 ----
__global__ void build_mats(const float* __restrict__ utab, unsigned short* __restrict__ mats) {
    int cid = blockIdx.x;
    int cc = BD[cid].cc;
    int EL = 1 << cc;
    __shared__ float2 Mm[32][32];
    int t = threadIdx.x;   // 64 threads
    for (int idx = t; idx < EL * EL; idx += 64) {
        int r = idx / EL, c = idx % EL;
        Mm[r][c] = make_float2(r == c ? 1.f : 0.f, 0.f);
    }
    __syncthreads();
    for (int g = 0; g < cc; ++g) {
        const float* u = utab + BD[cid].gi[g] * 8;
        unsigned lam = BD[cid].lam[g];
        int tot = EL * EL / 2;
        for (int idx = t; idx < tot; idx += 64) {
            int col = idx % EL; int p = idx / EL;
            unsigned v = (((unsigned)p >> g) << (g + 1)) | ((unsigned)p & ((1u << g) - 1u));
            unsigned y = v | (1u << g);
            int cpar = __popc(lam & v) & 1;
            float Ar, Ai, Br, Bi, Cr, Ci, Dr, Di;
            if (!cpar) { Ar=u[0];Ai=u[1];Br=u[2];Bi=u[3];Cr=u[4];Ci=u[5];Dr=u[6];Di=u[7]; }
            else       { Ar=u[6];Ai=u[7];Br=u[4];Bi=u[5];Cr=u[2];Ci=u[3];Dr=u[0];Di=u[1]; }
            float2 a = Mm[v][col], b = Mm[y][col];
            float2 nv = make_float2(Ar*a.x - Ai*a.y + Br*b.x - Bi*b.y,
                                    Ar*a.y + Ai*a.x + Br*b.y + Bi*b.x);
            float2 ny = make_float2(Cr*a.x - Ci*a.y + Dr*b.x - Di*b.y,
                                    Cr*a.y + Ci*a.x + Dr*b.y + Di*b.x);
            Mm[v][col] = nv; Mm[y][col] = ny;
        }
        __syncthreads();
    }
    unsigned short* dst = mats + (size_t)cid * 2048;
    for (int idx = t; idx < 1024; idx += 64) {
        int r = idx >> 5, k = idx & 31;
        float re = (r < EL && k < EL) ? Mm[r][k].x : 0.f;
        float im = (r < EL && k < EL) ? Mm[r][k].y : 0.f;
        dst[idx]        = __half_as_ushort(__float2half_rn(re));
        dst[1024 + idx] = __half_as_ushort(__float2half_rn(im));
    }
}

__device__ __forceinline__ float2 up16(unsigned u) {
    __half_raw h0; h0.x = (unsigned short)(u & 0xFFFFu);
    __half_raw h1; h1.x = (unsigned short)(u >> 16);
    return make_float2(__half2float(__half(h0)), __half2float(__half(h1)));
}
__device__ __forceinline__ unsigned dn16(float a, float b) {
    unsigned short ua = __half_as_ushort(__float2half_rn(a));
    unsigned short ub = __half_as_ushort(__float2half_rn(b));
    return (unsigned)ua | ((unsigned)ub << 16);
}
__device__ __forceinline__ half8_t h8(uint4 u) { return __builtin_bit_cast(half8_t, u); }

// ---- linear staging: global <-> LDS, fully coalesced (unchanged from r7) ----
template <int P, bool H>
__device__ __forceinline__ void stage_in(unsigned* __restrict__ tile16,
        float2* __restrict__ tile32, unsigned base, size_t boff,
        const unsigned* __restrict__ st16, const float2* __restrict__ st32,
        const float* __restrict__ in_re, const float* __restrict__ in_im) {
    constexpr PassDef pd = make_pass(P);
    #pragma unroll
    for (int it = 0; it < 16384 / (4 * NT); ++it) {
        unsigned i = 4u * ((unsigned)threadIdx.x + (unsigned)(it * NT));
        unsigned gtb = base;
        #pragma unroll
        for (int j = 2; j < 14; ++j) if ((i >> j) & 1u) gtb ^= pd.basis[j];
        unsigned sa = NSWZ(i);
        if constexpr (P == 0) {
            unsigned g4 = gtb ^ (gtb >> 4);
            unsigned gb = g4 & ~3u;
            unsigned lo = g4 & 3u;
            float4 vr = *(const float4*)(in_re + boff + gb);
            float4 vi = *(const float4*)(in_im + boff + gb);
            float r0 = vr.x, r1 = vr.y, r2 = vr.z, r3 = vr.w;
            float i0 = vi.x, i1 = vi.y, i2 = vi.z, i3 = vi.w;
            if (lo & 1u) { float tt;
                tt = r0; r0 = r1; r1 = tt;  tt = r2; r2 = r3; r3 = tt;
                tt = i0; i0 = i1; i1 = tt;  tt = i2; i2 = i3; i3 = tt; }
            if (lo & 2u) { float tt;
                tt = r0; r0 = r2; r2 = tt;  tt = r1; r1 = r3; r3 = tt;
                tt = i0; i0 = i2; i2 = tt;  tt = i1; i1 = i3; i3 = tt; }
            if constexpr (H) {
                *(uint2*)&tile16[sa]     = make_uint2(dn16(r0, i0), dn16(r1, i1));
                *(uint2*)&tile16[sa ^ 2] = make_uint2(dn16(r2, i2), dn16(r3, i3));
            } else {
                *(float4*)&tile32[sa]     = make_float4(r0, i0, r1, i1);
                *(float4*)&tile32[sa ^ 2] = make_float4(r2, i2, r3, i3);
            }
        } else if constexpr (H) {
            uint4 v = *(const uint4*)(st16 + boff + gtb);
            *(uint2*)&tile16[sa]     = make_uint2(v.x, v.y);
            *(uint2*)&tile16[sa ^ 2] = make_uint2(v.z, v.w);
        } else {
            float4 a = *(const float4*)(st32 + boff + gtb);
            float4 b = *(const float4*)(st32 + boff + gtb + 2);
            *(float4*)&tile32[sa]     = a;
            *(float4*)&tile32[sa ^ 2] = b;
        }
    }
}

template <int P, bool H>
__device__ __forceinline__ void stage_out(const unsigned* __restrict__ tile16,
        const float2* __restrict__ tile32, unsigned base, size_t boff,
        unsigned* __restrict__ st16, float2* __restrict__ st32,
        float2* __restrict__ out) {
    constexpr PassDef pd = make_pass(P);
    #pragma unroll
    for (int it = 0; it < 16384 / (4 * NT); ++it) {
        unsigned i = 4u * ((unsigned)threadIdx.x + (unsigned)(it * NT));
        unsigned gtb = base;
        #pragma unroll
        for (int j = 2; j < 14; ++j) if ((i >> j) & 1u) gtb ^= pd.basis[j];
        unsigned sa = NSWZ(i);
        if constexpr (H) {
            uint2 a = *(const uint2*)&tile16[sa];
            uint2 b = *(const uint2*)&tile16[sa ^ 2];
            if constexpr (P == 4) {
                float2 f0 = up16(a.x), f1 = up16(a.y), f2 = up16(b.x), f3 = up16(b.y);
                *(float4*)&out[boff + gtb]     = make_float4(f0.x, f0.y, f1.x, f1.y);
                *(float4*)&out[boff + gtb + 2] = make_float4(f2.x, f2.y, f3.x, f3.y);
            } else {
                *(uint4*)(st16 + boff + gtb) = make_uint4(a.x, a.y, b.x, b.y);
            }
        } else {
            float4 a = *(const float4*)&tile32[sa];
            float4 b = *(const float4*)&tile32[sa ^ 2];
            float2* dst = (P == 4) ? out : st32;
            *(float4*)&dst[boff + gtb]     = a;
            *(float4*)&dst[boff + gtb + 2] = b;
        }
    }
}

// ---- scalar cluster (fp32 fallback path) ----
template <int P, int CI>
__device__ __forceinline__ void do_cluster32(float2* __restrict__ tile32,
        unsigned base, const float* __restrict__ utab) {
    constexpr PassDef pd = make_pass(P);
    constexpr int CC = pd.cl[CI].c;
    constexpr int EL = 1 << CC;
    constexpr int NC = (1 << (14 - CC)) / NT;
    #pragma unroll
    for (int cc = 0; cc < NC; ++cc) {
        unsigned idx = (unsigned)threadIdx.x + (unsigned)(cc * NT);
        unsigned tb = 0;
        #pragma unroll
        for (int i = 0; i < 14 - CC; ++i) tb |= ((idx >> i) & 1u) << pd.cl[CI].np[i];
        unsigned ptb = NSWZ(tb);
        float xr[EL], xi[EL];
        #pragma unroll
        for (int v = 0; v < EL; ++v) {
            float2 f = tile32[ptb ^ pd.cl[CI].pcombo[v]]; xr[v] = f.x; xi[v] = f.y;
        }
        #pragma unroll
        for (int g = 0; g < CC; ++g) {
            const float* u = utab + pd.cl[CI].gi[g] * 8;
            int r0 = (__popc(pd.cl[CI].rho[g] & tb) + __popc(pd.cl[CI].wglob[g] & base)) & 1;
            float u0r = u[0], u0i = u[1], u1r = u[2], u1i = u[3];
            float u2r = u[4], u2i = u[5], u3r = u[6], u3i = u[7];
            float Ar = r0 ? u3r : u0r, Ai = r0 ? u3i : u0i;
            float Br = r0 ? u2r : u1r, Bi = r0 ? u2i : u1i;
            float Cr = r0 ? u1r : u2r, Ci_ = r0 ? u1i : u2i;
            float Dr = r0 ? u0r : u3r, Di = r0 ? u0i : u3i;
            #pragma unroll
            for (int v = 0; v < EL; ++v) {
                if (v & (1 << g)) continue;
                int cpar = __popc(pd.cl[CI].lam[g] & (unsigned)v) & 1;
                int y = v | (1 << g);
                float axr = xr[v], axi = xi[v], ayr = xr[y], ayi = xi[y];
                if (cpar == 0) {
                    xr[v] = Ar*axr - Ai*axi + Br*ayr - Bi*ayi;
                    xi[v] = Ar*axi + Ai*axr + Br*ayi + Bi*ayr;
                    xr[y] = Cr*axr - Ci_*axi + Dr*ayr - Di*ayi;
                    xi[y] = Cr*axi + Ci_*axr + Dr*ayi + Di*ayr;
                } else {
                    xr[v] = Dr*axr - Di*axi + Cr*ayr - Ci_*ayi;
                    xi[v] = Dr*axi + Di*axr + Cr*ayi + Ci_*ayr;
                    xr[y] = Br*axr - Bi*axi + Ar*ayr - Ai*ayi;
                    xi[y] = Br*axi + Bi*axr + Ar*ayi + Ai*ayr;
                }
            }
        }
        #pragma unroll
        for (int v = 0; v < EL; ++v)
            tile32[ptb ^ pd.cl[CI].pcombo[v]] = make_float2(xr[v], xi[v]);
    }
}

// ---- MFMA cluster, CC=5: 32x32 matrix via 8x mfma_f32_32x32x16_f16 ----
template <int P, int CI>
__device__ __forceinline__ void mfma_cluster5(unsigned* __restrict__ tile16,
        unsigned base, const unsigned short* __restrict__ mats) {
    constexpr PassDef pd = make_pass(P);
    constexpr Cluster C = pd.cl[CI];
    constexpr int cid = (P < 4) ? P * 3 + CI : 12 + CI;
    const unsigned short* mb = mats + (size_t)cid * 2048;
    int wid = threadIdx.x >> 6;
    int l = threadIdx.x & 63;
    int col = l & 31, hi = l >> 5;

    // A frags: Mr/Mi, K-halves kk0/kk1. slot (hi,j) = M[row][kk*16 + hi*8 + j]
    half8_t Ar0 = h8(*(const uint4*)(mb +        col * 32 +      hi * 8));
    half8_t Ar1 = h8(*(const uint4*)(mb +        col * 32 + 16 + hi * 8));
    half8_t Ai0 = h8(*(const uint4*)(mb + 1024 + col * 32 +      hi * 8));
    half8_t Ai1 = h8(*(const uint4*)(mb + 1024 + col * 32 + 16 + hi * 8));

    for (int t = 0; t < 2; ++t) {
        int ci_ = (wid * 2 + t) * 32 + col;
        unsigned tb = 0;
        #pragma unroll
        for (int i = 0; i < 9; ++i) tb |= (((unsigned)ci_ >> i) & 1u) << C.np[i];
        unsigned psh = 0;
        #pragma unroll
        for (int k = 0; k < 5; ++k) {
            unsigned pk = (unsigned)((__popc(C.rho[k] & tb) + __popc(C.wglob[k] & base)) & 1);
            psh ^= pk ? C.pst[k] : 0u;
        }
        unsigned sb = NSWZ(tb) ^ psh;
        unsigned sb2 = sb ^ (hi ? C.pcombo[8] : 0u);

        unsigned r0[8], r1[8];
        #pragma unroll
        for (int j = 0; j < 8; ++j) r0[j] = tile16[sb2 ^ C.pcombo[j]];
        #pragma unroll
        for (int j = 0; j < 8; ++j) r1[j] = tile16[sb2 ^ C.pcombo[16] ^ C.pcombo[j]];

        uint4 br0, bi0, br1, bi1;
        br0.x = (r0[0] & 0xffffu) | (r0[1] << 16);  bi0.x = (r0[0] >> 16) | (r0[1] & 0xffff0000u);
        br0.y = (r0[2] & 0xffffu) | (r0[3] << 16);  bi0.y = (r0[2] >> 16) | (r0[3] & 0xffff0000u);
        br0.z = (r0[4] & 0xffffu) | (r0[5] << 16);  bi0.z = (r0[4] >> 16) | (r0[5] & 0xffff0000u);
        br0.w = (r0[6] & 0xffffu) | (r0[7] << 16);  bi0.w = (r0[6] >> 16) | (r0[7] & 0xffff0000u);
        br1.x = (r1[0] & 0xffffu) | (r1[1] << 16);  bi1.x = (r1[0] >> 16) | (r1[1] & 0xffff0000u);
        br1.y = (r1[2] & 0xffffu) | (r1[3] << 16);  bi1.y = (r1[2] >> 16) | (r1[3] & 0xffff0000u);
        br1.z = (r1[4] & 0xffffu) | (r1[5] << 16);  bi1.z = (r1[4] >> 16) | (r1[5] & 0xffff0000u);
        br1.w = (r1[6] & 0xffffu) | (r1[7] << 16);  bi1.w = (r1[6] >> 16) | (r1[7] & 0xffff0000u);
        uint4 bn0 = make_uint4(bi0.x ^ 0x80008000u, bi0.y ^ 0x80008000u,
                               bi0.z ^ 0x80008000u, bi0.w ^ 0x80008000u);
        uint4 bn1 = make_uint4(bi1.x ^ 0x80008000u, bi1.y ^ 0x80008000u,
                               bi1.z ^ 0x80008000u, bi1.w ^ 0x80008000u);

        f32x16_t cr = 0.f, ci = 0.f;
        cr = __builtin_amdgcn_mfma_f32_32x32x16_f16(Ar0, h8(br0), cr, 0, 0, 0);
        cr = __builtin_amdgcn_mfma_f32_32x32x16_f16(Ai0, h8(bn0), cr, 0, 0, 0);
        ci = __builtin_amdgcn_mfma_f32_32x32x16_f16(Ai0, h8(br0), ci, 0, 0, 0);
        ci = __builtin_amdgcn_mfma_f32_32x32x16_f16(Ar0, h8(bi0), ci, 0, 0, 0);
        cr = __builtin_amdgcn_mfma_f32_32x32x16_f16(Ar1, h8(br1), cr, 0, 0, 0);
        cr = __builtin_amdgcn_mfma_f32_32x32x16_f16(Ai1, h8(bn1), cr, 0, 0, 0);
        ci = __builtin_amdgcn_mfma_f32_32x32x16_f16(Ai1, h8(br1), ci, 0, 0, 0);
        ci = __builtin_amdgcn_mfma_f32_32x32x16_f16(Ar1, h8(bi1), ci, 0, 0, 0);

        // C layout: col = l&31, row = (reg&3) + 8*(reg>>2) + 4*hi
        unsigned sbE = sb ^ (hi ? C.pcombo[4] : 0u);
        #pragma unroll
        for (int reg = 0; reg < 16; ++reg) {
            constexpr int dummy = 0; (void)dummy;
            int rowlab = (reg & 3) | ((reg >> 2) << 3);
            tile16[sbE ^ C.pcombo[rowlab]] = dn16(cr[reg], ci[reg]);
        }
    }
}

// ---- MFMA cluster, CC=4: 16x16 matrix via 4x mfma_f32_16x16x32_f16 (K-padded) ----
template <int P, int CI>
__device__ __forceinline__ void mfma_cluster4(unsigned* __restrict__ tile16,
        unsigned base, const unsigned short* __restrict__ mats) {
    constexpr PassDef pd = make_pass(P);
    constexpr Cluster C = pd.cl[CI];
    constexpr int cid = (P < 4) ? P * 3 + CI : 12 + CI;
    const unsigned short* mb = mats + (size_t)cid * 2048;
    int wid = threadIdx.x >> 6;
    int l = threadIdx.x & 63;
    int col = l & 15, q = l >> 4;

    // A frags: [16 rows][32 k] padded (k>=16 zero). slot (q,j) = M[row][q*8+j]
    half8_t Ar = h8(*(const uint4*)(mb +        col * 32 + q * 8));
    half8_t Ai = h8(*(const uint4*)(mb + 1024 + col * 32 + q * 8));

    for (int t = 0; t < 8; ++t) {
        int ci_ = (wid * 8 + t) * 16 + col;
        unsigned tb = 0;
        #pragma unroll
        for (int i = 0; i < 10; ++i) tb |= (((unsigned)ci_ >> i) & 1u) << C.np[i];
        unsigned psh = 0;
        #pragma unroll
        for (int k = 0; k < 4; ++k) {
            unsigned pk = (unsigned)((__popc(C.rho[k] & tb) + __popc(C.wglob[k] & base)) & 1);
            psh ^= pk ? C.pst[k] : 0u;
        }
        unsigned sb = NSWZ(tb) ^ psh;

        uint4 br = make_uint4(0u, 0u, 0u, 0u), bi = make_uint4(0u, 0u, 0u, 0u);
        if (q < 2) {
            unsigned sb2 = sb ^ (q ? C.pcombo[8] : 0u);
            unsigned rr[8];
            #pragma unroll
            for (int j = 0; j < 8; ++j) rr[j] = tile16[sb2 ^ C.pcombo[j]];
            br.x = (rr[0] & 0xffffu) | (rr[1] << 16);  bi.x = (rr[0] >> 16) | (rr[1] & 0xffff0000u);
            br.y = (rr[2] & 0xffffu) | (rr[3] << 16);  bi.y = (rr[2] >> 16) | (rr[3] & 0xffff0000u);
            br.z = (rr[4] & 0xffffu) | (rr[5] << 16);  bi.z = (rr[4] >> 16) | (rr[5] & 0xffff0000u);
            br.w = (rr[6] & 0xffffu) | (rr[7] << 16);  bi.w = (rr[6] >> 16) | (rr[7] & 0xffff0000u);
        }
        uint4 bn = make_uint4(bi.x ^ 0x80008000u, bi.y ^ 0x80008000u,
                              bi.z ^ 0x80008000u, bi.w ^ 0x80008000u);

        f32x4_t cr = 0.f, ci = 0.f;
        cr = __builtin_amdgcn_mfma_f32_16x16x32_f16(Ar, h8(br), cr, 0, 0, 0);
        cr = __builtin_amdgcn_mfma_f32_16x16x32_f16(Ai, h8(bn), cr, 0, 0, 0);
        ci = __builtin_amdgcn_mfma_f32_16x16x32_f16(Ai, h8(br), ci, 0, 0, 0);
        ci = __builtin_amdgcn_mfma_f32_16x16x32_f16(Ar, h8(bi), ci, 0, 0, 0);

        // C layout: col = l&15, row = q*4 + reg
        unsigned qterm = ((q & 1) ? C.pcombo[4] : 0u) ^ ((q & 2) ? C.pcombo[8] : 0u);
        unsigned sbE = sb ^ qterm;
        #pragma unroll
        for (int reg = 0; reg < 4; ++reg) {
            tile16[sbE ^ C.pcombo[reg]] = dn16(cr[reg], ci[reg]);
        }
    }
}

template <int P, int CI, bool H>
__device__ __forceinline__ void run_cluster(unsigned* __restrict__ tile16,
        float2* __restrict__ tile32, unsigned base,
        const float* __restrict__ utab, const unsigned short* __restrict__ mats) {
    constexpr PassDef pd = make_pass(P);
    if constexpr (H && pd.cl[CI].c == 5) {
        mfma_cluster5<P, CI>(tile16, base, mats);
    } else if constexpr (H && pd.cl[CI].c == 4) {
        mfma_cluster4<P, CI>(tile16, base, mats);
    } else {
        do_cluster32<P, CI>(tile32, base, utab);
    }
}

template <int P, bool H>
__global__ __launch_bounds__(NT) void pass_kernel(unsigned* __restrict__ st16,
        float2* __restrict__ st32, float2* __restrict__ out,
        const float* __restrict__ utab, const unsigned short* __restrict__ mats,
        const float* __restrict__ in_re, const float* __restrict__ in_im) {
    extern __shared__ unsigned char smem_raw[];
    unsigned* tile16 = reinterpret_cast<unsigned*>(smem_raw);
    float2*  tile32 = reinterpret_cast<float2*>(smem_raw);
    constexpr PassDef pd = make_pass(P);

    unsigned bid = blockIdx.x;
    unsigned batch = bid >> 2;
    unsigned fr = bid & 3u;
    unsigned base = ((fr & 1u) << pd.fb0) | (((fr >> 1) & 1u) << pd.fb1);
    size_t boff = (size_t)batch << 16;

    stage_in<P, H>(tile16, tile32, base, boff, st16, st32, in_re, in_im);
    __syncthreads();
    run_cluster<P, 0, H>(tile16, tile32, base, utab, mats);
    __syncthreads();
    run_cluster<P, 1, H>(tile16, tile32, base, utab, mats);
    __syncthreads();
    if constexpr (make_pass(P).nclust > 2) {
        run_cluster<P, 2, H>(tile16, tile32, base, utab, mats);
        __syncthreads();
    }
    stage_out<P, H>(tile16, tile32, base, boff, st16, st32, out);
}

extern "C" void kernel_launch(void* const* d_in, const int* in_sizes, int n_in,
                              void* d_out, int out_size, void* d_ws, size_t ws_size,
                              hipStream_t stream) {
    const float* in_re  = (const float*)d_in[0];
    const float* in_im  = (const float*)d_in[1];
    const float* params = (const float*)d_in[2];
    float2* out = (float2*)d_out;

    const size_t STATE_BYTES = 256ull * 65536ull * 4ull;   // packed fp16 state (2^26 B)
    bool h = (ws_size >= STATE_BYTES + 65536);

    unsigned* st16 = (unsigned*)d_ws;
    float2*   st32 = out;                                  // fp32 fallback: in-place in d_out
    float* utab = h ? (float*)((char*)d_ws + STATE_BYTES) : (float*)d_ws;
    unsigned short* mats = h ? (unsigned short*)((char*)d_ws + STATE_BYTES + 4096) : nullptr;

    prep_gates<<<dim3(1), dim3(64), 0, stream>>>(params, utab);

    if (h) {
        build_mats<<<dim3(14), dim3(64), 0, stream>>>(utab, mats);
        const size_t SH = 16384 * 4;
        pass_kernel<0, true><<<dim3(1024), dim3(NT), SH, stream>>>(st16, st32, out, utab, mats, in_re, in_im);
        pass_kernel<1, true><<<dim3(1024), dim3(NT), SH, stream>>>(st16, st32, out, utab, mats, in_re, in_im);
        pass_kernel<2, true><<<dim3(1024), dim3(NT), SH, stream>>>(st16, st32, out, utab, mats, in_re, in_im);
        pass_kernel<3, true><<<dim3(1024), dim3(NT), SH, stream>>>(st16, st32, out, utab, mats, in_re, in_im);
        pass_kernel<4, true><<<dim3(1024), dim3(NT), SH, stream>>>(st16, st32, out, utab, mats, in_re, in_im);
    } else {
        const size_t SH = 16384 * 8;
        pass_kernel<0, false><<<dim3(1024), dim3(NT), SH, stream>>>(st16, st32, out, utab, nullptr, in_re, in_im);
        pass_kernel<1, false><<<dim3(1024), dim3(NT), SH, stream>>>(st16, st32, out, utab, nullptr, in_re, in_im);
        pass_kernel<2, false><<<dim3(1024), dim3(NT), SH, stream>>>(st16, st32, out, utab, nullptr, in_re, in_im);
        pass_kernel<3, false><<<dim3(1024), dim3(NT), SH, stream>>>(st16, st32, out, utab, nullptr, in_re, in_im);
        pass_kernel<4, false><<<dim3(1024), dim3(NT), SH, stream>>>(st16, st32, out, utab, nullptr, in_re, in_im);
    }
}